// Round 19
// baseline (162.501 us; speedup 1.0000x reference)
//
#include <hip/hip_runtime.h>
#include <math.h>

// ---------------------------------------------------------------------------
// out = x + W2·gelu_fftlow(W1·x + b1) + b2
//  prep_w:       W1,W2 f32 -> bf16 fragment-direct tables + swizzled
//                Dirichlet table RbF (r18-verified).
//  gemm1_mfma:   xs1 = gelu(X·W1^T + b1); NEW: BM=64 (grid 1024) — same
//                traffic, ~2x resident blocks to hide the K-tile barrier
//                drain (acc[2][3], lighter VGPR).
//  fftfilt_mfma: per-plane circular low-pass; Rb from RbF (r18-verified).
//  gemm2_mfma:   r15/r17-VERIFIED: nt last-touch streams + XCD swizzle.
// ws: xs1 (25.2MB) | xs2 (25.2MB) | W1F (288KB) | W2F (288KB) | RbF (8KB)
// ---------------------------------------------------------------------------

typedef unsigned short u16;
typedef __attribute__((ext_vector_type(8))) short bf16x8;
typedef __attribute__((ext_vector_type(4))) float f32x4;

__device__ __forceinline__ float bf2f(u16 u) {
    union { unsigned int i; float f; } v; v.i = ((unsigned int)u) << 16; return v.f;
}
__device__ __forceinline__ u16 f2bf(float f) {
    union { unsigned int i; float f; } v; v.f = f;
    unsigned int r = v.i + 0x7FFFu + ((v.i >> 16) & 1u);   // RNE
    return (u16)(r >> 16);
}
__device__ __forceinline__ unsigned cvtpk(float lo, float hi) {
    unsigned r;
    asm("v_cvt_pk_bf16_f32 %0, %1, %2" : "=v"(r) : "v"(lo), "v"(hi));
    return r;
}
// LDS-only barrier (gemm2 steady state; measured neutral vs __syncthreads).
__device__ __forceinline__ void bar_lgkm() {
    asm volatile("s_waitcnt lgkmcnt(0)" ::: "memory");
    __builtin_amdgcn_s_barrier();
    asm volatile("" ::: "memory");
}

// row XOR-swizzle, u16 units; rowU16 multiple of 64 (128B rows)
__device__ __forceinline__ int swz(int row, int rowU16, int colU16) {
    int cb = colU16 & ~7;
    int ci = colU16 & 7;
    return row * rowU16 + (cb ^ ((row & 7) << 3)) + ci;
}
// gemm2 As swizzle
__device__ __forceinline__ int swz2(int row, int colU16) {
    int cb = colU16 >> 3;
    int ci = colU16 & 7;
    cb ^= (row & 7) ^ ((row >> 3) & 7);
    return row * 192 + (cb << 3) + ci;
}
// fftfilt's own swizzle (verified)
__device__ __forceinline__ int swzb(int row, int byteInRow) {
    return (row << 7) + (byteInRow ^ ((row & 7) << 4));
}
__device__ __forceinline__ int swzi(int row, int col) {
    return swzb(row, col << 1) >> 1;
}

#define PI_32 0.09817477042468103f

// ===================== prep_w: weight tables + Dirichlet table =============
__global__ __launch_bounds__(256) void prep_w(
    const float* __restrict__ W1, const float* __restrict__ W2,
    u16* __restrict__ W1F, u16* __restrict__ W2F, u16* __restrict__ RBF)
{
    int tid = blockIdx.x * 256 + threadIdx.x;
    if (tid < 18432) {
        int c = tid;
        int l  = c & 63;
        int kk = (c >> 6) & 1;
        int r  = c >> 7;            // (kt*4+g)*3 + nj
        int nj = r % 3;
        int gkt = r / 3;            // kt*4+g
        int g  = gkt & 3;
        int kt = gkt >> 2;
        int row = g * 48 + nj * 16 + (l & 15);
        int col = kt * 64 + kk * 32 + ((l >> 4) << 3);
        const float* s = &W1[(size_t)row * 768 + col];
        u16* dst = &W1F[(size_t)c * 8];
        #pragma unroll
        for (int j = 0; j < 8; ++j) dst[j] = f2bf(s[j]);
    } else if (tid < 36864) {
        int c = tid - 18432;
        int l  = c & 63;
        int kk = (c >> 6) % 6;
        int r  = (c >> 6) / 6;      // (ct*2+cw)*2 + cj
        int cj = r & 1;
        int cwct = r >> 1;
        int cw = cwct & 1;
        int ct = cwct >> 1;
        int row = ct * 64 + cw * 32 + cj * 16 + (l & 15);
        int col = kk * 32 + ((l >> 4) << 3);
        const float* s = &W2[(size_t)row * 192 + col];
        u16* dst = &W2F[(size_t)c * 8];
        #pragma unroll
        for (int j = 0; j < 8; ++j) dst[j] = f2bf(s[j]);
    } else if (tid < 40960) {
        int c = tid - 36864;        // 0..4095: Rb entry (i,j), swizzled store
        int i = c >> 6, j = c & 63;
        int d = (i - j) & 63;
        float rr = 0.f;
        for (int k = -16; k < 16; ++k) {
            int md = ((k * d) % 64 + 64) % 64;
            rr += cosf((float)md * PI_32);
        }
        RBF[swzi(i, j)] = f2bf(rr * 0.015625f);
    }
}

// ============================ GEMM1 (MFMA) =================================
// grid 1024, 512 threads (8 waves: 2m x 4n), BM=64, BN=192, BK=64
// A double-buffered in LDS (16KB total, one barrier/K-tile); B direct W1F.
__global__ __launch_bounds__(512) void gemm1_mfma(
    const float* __restrict__ X, const u16* __restrict__ W1F,
    const float* __restrict__ b1, u16* __restrict__ XS1)
{
    __shared__ u16 As[2][64 * 64];
    const int t  = threadIdx.x, wv = t >> 6, l = t & 63;
    const int m0 = blockIdx.x * 64;
    const int bb = m0 >> 12, mp0 = m0 & 4095;
    const int fr  = l & 15;
    const int fko = (l >> 4) << 3;
    const int wm = (wv & 1) * 32, g = wv >> 1, wn = g * 48;
    const int arow = t >> 3, ac8 = (t & 7) << 3;   // 64 rows x 64 cols, 8 f32/thr
    const float* aptr = &X[(size_t)(m0 + arow) * 768 + ac8];

    float4 f0 = *(const float4*)(aptr);
    float4 f1 = *(const float4*)(aptr + 4);

    f32x4 acc[2][3];
    #pragma unroll
    for (int i = 0; i < 2; ++i)
        #pragma unroll
        for (int j = 0; j < 3; ++j)
            acc[i][j] = (f32x4){0.f, 0.f, 0.f, 0.f};

    for (int kt = 0; kt < 12; ++kt) {
        u16* Ab = &As[kt & 1][0];
        {
            uint4 q;
            q.x = cvtpk(f0.x, f0.y); q.y = cvtpk(f0.z, f0.w);
            q.z = cvtpk(f1.x, f1.y); q.w = cvtpk(f1.z, f1.w);
            *(uint4*)&Ab[swz(arow, 64, ac8)] = q;
        }
        if (kt < 11) {   // prefetch next K-tile while MFMA runs
            const float* np = aptr + (kt + 1) * 64;
            f0 = *(const float4*)(np);
            f1 = *(const float4*)(np + 4);
        }
        __syncthreads();
        #pragma unroll
        for (int kk = 0; kk < 2; ++kk) {
            const size_t base = ((size_t)((kt * 4 + g) * 3) * 2 + kk) * 512 + (size_t)l * 8;
            bf16x8 b0  = *(const bf16x8*)&W1F[base];
            bf16x8 b1v = *(const bf16x8*)&W1F[base + 1024];   // nj=1
            bf16x8 b2v = *(const bf16x8*)&W1F[base + 2048];   // nj=2
            #pragma unroll
            for (int mi = 0; mi < 2; ++mi) {
                bf16x8 a = *(bf16x8*)&Ab[swz(wm + mi * 16 + fr, 64, kk * 32 + fko)];
                acc[mi][0] = __builtin_amdgcn_mfma_f32_16x16x32_bf16(a, b0,  acc[mi][0], 0, 0, 0);
                acc[mi][1] = __builtin_amdgcn_mfma_f32_16x16x32_bf16(a, b1v, acc[mi][1], 0, 0, 0);
                acc[mi][2] = __builtin_amdgcn_mfma_f32_16x16x32_bf16(a, b2v, acc[mi][2], 0, 0, 0);
            }
        }
        // no second barrier: double-buffered
    }

    // ---- epilogue: bias + exact gelu -> xs1 [d][m'] ----
    const int mr = mp0 + wm + (l >> 4) * 4;
    #pragma unroll
    for (int nj = 0; nj < 3; ++nj) {
        const int d = wn + nj * 16 + fr;
        const float bias = b1[d];
        u16* dst = XS1 + ((size_t)(bb * 192 + d) << 12);
        #pragma unroll
        for (int mi = 0; mi < 2; ++mi) {
            float v0, v1, v2, v3;
            v0 = acc[mi][nj][0] + bias; v0 = 0.5f*v0*(1.f+erff(v0*0.70710678118f));
            v1 = acc[mi][nj][1] + bias; v1 = 0.5f*v1*(1.f+erff(v1*0.70710678118f));
            v2 = acc[mi][nj][2] + bias; v2 = 0.5f*v2*(1.f+erff(v2*0.70710678118f));
            v3 = acc[mi][nj][3] + bias; v3 = 0.5f*v3*(1.f+erff(v3*0.70710678118f));
            uint2 pk;
            pk.x = cvtpk(v0, v1);
            pk.y = cvtpk(v2, v3);
            *(uint2*)&dst[mr + mi * 16] = pk;
        }
    }
}

// ===================== FFT low-pass: 1 plane / 256-thread block ============
// 4 waves split the 16-tile stages (wave wv owns ti = wv). LDS 24KB.
// Rb table linear-copied from precomputed RbF (L2-hot). (r18-verified)
__global__ __launch_bounds__(256) void fftfilt_mfma(
    const u16* __restrict__ XS1, u16* __restrict__ XS2,
    const u16* __restrict__ RBF)
{
    __shared__ u16  Rb[64 * 64];     // 8KB, R table (swizzled, symmetric)
    __shared__ u16  P [64 * 64];     // 8KB, plane; reused for |Y|
    __shared__ u16  Tt[64 * 64];     // 8KB, (P·R)^T

    const int t  = threadIdx.x;
    const int wv = t >> 6;
    const int l  = t & 63;

    const size_t base = (size_t)blockIdx.x << 12;
    const u16* src = XS1 + base;
    u16*       dst = XS2 + base;

    // ---- Rb: linear copy of precomputed swizzled table (2 x 16B/thread) ----
    #pragma unroll
    for (int it = 0; it < 2; ++it) {
        const int e0 = (it * 256 + t) * 8;
        *(bf16x8*)&Rb[e0] = *(const bf16x8*)&RBF[e0];
    }
    // ---- load plane (512 x 16B chunks over 256 threads) ----
    #pragma unroll
    for (int it = 0; it < 2; ++it) {
        const int e0 = (it * 256 + t) * 8;
        bf16x8 v = *(const bf16x8*)&src[e0];
        *(bf16x8*)&P[swzi(e0 >> 6, e0 & 63)] = v;
    }
    __syncthreads();

    // ---- rank-4 correction moments (each wave computes identical p1..p4) --
    float vc = 0.f, vs = 0.f;
    #pragma unroll
    for (int jc = 0; jc < 8; ++jc) {
        bf16x8 v = *(bf16x8*)&P[swzi(l, jc * 8)];
        vc += bf2f((u16)v[0]) - bf2f((u16)v[2]) + bf2f((u16)v[4]) - bf2f((u16)v[6]);
        vs += bf2f((u16)v[1]) - bf2f((u16)v[3]) + bf2f((u16)v[5]) - bf2f((u16)v[7]);
    }
    const float cl = (l & 1) ? 0.f : ((l & 2) ? -1.f : 1.f);
    const float sl = (l & 1) ? ((l & 2) ? -1.f : 1.f) : 0.f;
    float p1 = cl * vc, p2 = cl * vs, p3 = sl * vc, p4 = sl * vs;
    #pragma unroll
    for (int off = 32; off; off >>= 1) {
        p1 += __shfl_xor(p1, off);
        p2 += __shfl_xor(p2, off);
        p3 += __shfl_xor(p3, off);
        p4 += __shfl_xor(p4, off);
    }

    const int fr = l & 15;
    const int fk = (l >> 4) << 4;
    const int ti = wv;                      // wave owns one ti block

    // ---- stage 1: T1 = P·R (tiles ti=wv, tj=0..3), stored transposed ----
    #pragma unroll
    for (int tj = 0; tj < 4; ++tj) {
        f32x4 acc = {0.f, 0.f, 0.f, 0.f};
        #pragma unroll
        for (int kk = 0; kk < 2; ++kk) {
            bf16x8 a = *(bf16x8*)&P [swzb(ti * 16 + fr, (kk << 6) + fk) >> 1];
            bf16x8 b = *(bf16x8*)&Rb[swzb(tj * 16 + fr, (kk << 6) + fk) >> 1];
            acc = __builtin_amdgcn_mfma_f32_16x16x32_bf16(a, b, acc, 0, 0, 0);
        }
        const int n2 = tj * 16 + fr;
        const int w0 = ti * 16 + ((l >> 4) << 2);
        uint2 pk;
        pk.x = cvtpk(acc[0], acc[1]);
        pk.y = cvtpk(acc[2], acc[3]);
        *(uint2*)&Tt[swzb(n2, w0 << 1) >> 1] = pk;
    }
    __syncthreads();

    // ---- stage 2: Y = R·T1 + corr; |Y| -> P (rows ti*16..) ----
    const float inv4096 = 1.f / 4096.f;
    #pragma unroll
    for (int tj = 0; tj < 4; ++tj) {
        f32x4 acc = {0.f, 0.f, 0.f, 0.f};
        #pragma unroll
        for (int kk = 0; kk < 2; ++kk) {
            bf16x8 a = *(bf16x8*)&Rb[swzb(ti * 16 + fr, (kk << 6) + fk) >> 1];
            bf16x8 b = *(bf16x8*)&Tt[swzb(tj * 16 + fr, (kk << 6) + fk) >> 1];
            acc = __builtin_amdgcn_mfma_f32_16x16x32_bf16(a, b, acc, 0, 0, 0);
        }
        const int a0   = ti * 16 + ((l >> 4) << 2);
        const int bcol = tj * 16 + fr;
        const float cb = (bcol & 1) ? 0.f : ((bcol & 2) ? -1.f : 1.f);
        const float sb = (bcol & 1) ? ((bcol & 2) ? -1.f : 1.f) : 0.f;
        #pragma unroll
        for (int r = 0; r < 4; ++r) {
            const int aa = a0 + r;
            const float ca = (aa & 1) ? 0.f : ((aa & 2) ? -1.f : 1.f);
            const float sa = (aa & 1) ? ((aa & 2) ? -1.f : 1.f) : 0.f;
            const float corr = inv4096 *
                (p2 * sa * cb - p1 * sa * sb - p4 * ca * cb + p3 * ca * sb);
            P[swzi(aa, bcol)] = f2bf(fabsf(acc[r] + corr));
        }
    }
    __syncthreads();

    // ---- coalesced copy-out ----
    #pragma unroll
    for (int it = 0; it < 2; ++it) {
        const int e0 = (it * 256 + t) * 8;
        bf16x8 v = *(bf16x8*)&P[swzi(e0 >> 6, e0 & 63)];
        *(bf16x8*)&dst[e0] = v;
    }
}

// ============================ GEMM2 (MFMA) =================================
// r15/r17-VERIFIED: grid 512, 256 threads (4 waves: 2m x 2c), BM=128;
// nontemporal xs2/X loads and OUT stores (all last-touch); XCD swizzle.
__global__ __launch_bounds__(256, 2) void gemm2_mfma(
    const u16* __restrict__ XS2, const u16* __restrict__ W2F,
    const float* __restrict__ b2, const float* __restrict__ X,
    float* __restrict__ OUT)
{
    __shared__ float Ot[2][128 * 68];     // 69632 B; As overlays (dead after areg)
    u16* As = (u16*)&Ot[0][0];            // [m][d] swz2, 128*192 u16 = 48KB
    const int t  = threadIdx.x, wv = t >> 6, l = t & 63;
    const int bid = ((blockIdx.x & 7) << 6) | (blockIdx.x >> 3);   // XCD swizzle
    const int m0 = bid * 128;
    const int b  = m0 >> 12, mp0 = m0 & 4095;
    const int fr  = l & 15;
    const int fko = (l >> 4) << 3;
    const int wm = (wv & 1) * 64, cw = wv >> 1, wc = cw * 32;

    // ---- fused transpose staging: read [d][m'] coalesced (nt), scatter ----
    #pragma unroll
    for (int i = 0; i < 12; ++i) {
        const int e = t + i * 256;        // 0..3071
        const int d = e >> 4, mc = e & 15;
        bf16x8 v = __builtin_nontemporal_load(
            (const bf16x8*)&XS2[((size_t)(b * 192 + d) << 12) + mp0 + mc * 8]);
        #pragma unroll
        for (int j = 0; j < 8; ++j)
            As[swz2(mc * 8 + j, d)] = (u16)v[j];
    }
    __syncthreads();

    // ---- A fragments to registers ----
    bf16x8 areg[4][6];
    #pragma unroll
    for (int mi = 0; mi < 4; ++mi)
        #pragma unroll
        for (int kk = 0; kk < 6; ++kk)
            areg[mi][kk] = *(bf16x8*)&As[swz2(wm + mi * 16 + fr, kk * 32 + fko)];
    __syncthreads();                      // As now dead; Ot safe to write

    // epilogue read mapping (fixed per thread)
    const int erow = t >> 4;              // + p*16
    const int ec4  = (t & 15) << 2;       // f32 col

    // ---- prefetch X for tile ct=0 (nontemporal: streamed once) ----
    f32x4 xreg[8];
    #pragma unroll
    for (int p = 0; p < 8; ++p)
        xreg[p] = __builtin_nontemporal_load(
            (const f32x4*)&X[(size_t)(m0 + erow + p * 16) * 768 + ec4]);

    // ---- 12 c-tiles, B direct from W2F (L2-hot, cached) ----
    for (int ct = 0; ct < 12; ++ct) {
        f32x4 acc[4][2];   // [mi][cj]; c = lane&15, m = (l>>4)*4 + reg
        #pragma unroll
        for (int i = 0; i < 4; ++i) {
            acc[i][0] = (f32x4){0.f, 0.f, 0.f, 0.f};
            acc[i][1] = (f32x4){0.f, 0.f, 0.f, 0.f};
        }
        #pragma unroll
        for (int kk = 0; kk < 6; ++kk) {
            const size_t base = (((size_t)(ct * 2 + cw) * 2) * 6 + kk) * 512 + (size_t)l * 8;
            bf16x8 bv0 = *(const bf16x8*)&W2F[base];
            bf16x8 bv1 = *(const bf16x8*)&W2F[base + 3072];   // cj=1
            #pragma unroll
            for (int mi = 0; mi < 4; ++mi) {
                acc[mi][0] = __builtin_amdgcn_mfma_f32_16x16x32_bf16(areg[mi][kk], bv0, acc[mi][0], 0, 0, 0);
                acc[mi][1] = __builtin_amdgcn_mfma_f32_16x16x32_bf16(areg[mi][kk], bv1, acc[mi][1], 0, 0, 0);
            }
        }
        // ---- stage acc into f32 LDS tile (dbuf) ----
        float* Ob = &Ot[ct & 1][0];
        #pragma unroll
        for (int cj = 0; cj < 2; ++cj) {
            const int cc = wc + cj * 16 + fr;
            #pragma unroll
            for (int mi = 0; mi < 4; ++mi) {
                const int mrow = wm + mi * 16 + (l >> 4) * 4;
                Ob[(mrow + 0) * 68 + cc] = acc[mi][cj][0];
                Ob[(mrow + 1) * 68 + cc] = acc[mi][cj][1];
                Ob[(mrow + 2) * 68 + cc] = acc[mi][cj][2];
                Ob[(mrow + 3) * 68 + cc] = acc[mi][cj][3];
            }
        }
        // ---- issue next tile's X loads BEFORE the barrier (nt) ----
        f32x4 xnext[8];
        if (ct < 11) {
            #pragma unroll
            for (int p = 0; p < 8; ++p)
                xnext[p] = __builtin_nontemporal_load(
                    (const f32x4*)&X[(size_t)(m0 + erow + p * 16) * 768
                                     + (ct + 1) * 64 + ec4]);
        }
        bar_lgkm();     // LDS-only drain; stores/loads stay in flight
        // ---- coalesced RMW: 256B bursts along c, nontemporal stores ----
        const int c0 = ct * 64;
        const float4 bv4 = *(const float4*)&b2[c0 + ec4];
        #pragma unroll
        for (int p = 0; p < 8; ++p) {
            const int row = erow + p * 16;
            const float* s = &Ob[row * 68 + ec4];
            const size_t off = (size_t)(m0 + row) * 768 + c0 + ec4;
            f32x4 o;
            o[0] = (s[0] + bv4.x) + xreg[p][0];
            o[1] = (s[1] + bv4.y) + xreg[p][1];
            o[2] = (s[2] + bv4.z) + xreg[p][2];
            o[3] = (s[3] + bv4.w) + xreg[p][3];
            __builtin_nontemporal_store(o, (f32x4*)&OUT[off]);
        }
        if (ct < 11) {
            #pragma unroll
            for (int p = 0; p < 8; ++p) xreg[p] = xnext[p];
        }
        // next iteration writes the other Ot buffer; reads of this one are
        // protected by the barrier inside the next iteration.
    }
}

// ---------------------------------------------------------------------------
extern "C" void kernel_launch(void* const* d_in, const int* in_sizes, int n_in,
                              void* d_out, int out_size, void* d_ws, size_t ws_size,
                              hipStream_t stream) {
    (void)in_sizes; (void)n_in; (void)out_size; (void)ws_size;
    const float* X  = (const float*)d_in[0];
    const float* W1 = (const float*)d_in[1];
    const float* b1 = (const float*)d_in[2];
    const float* W2 = (const float*)d_in[3];
    const float* b2 = (const float*)d_in[4];
    float* OUT = (float*)d_out;

    u16* reg0 = (u16*)d_ws;                              // xs1
    u16* reg1 = reg0 + (size_t)16 * 192 * 4096;          // xs2
    u16* W1F  = reg1 + (size_t)16 * 192 * 4096;          // 147456 u16
    u16* W2F  = W1F + 147456;                            // 147456 u16
    u16* RBF  = W2F + 147456;                            // 4096 u16

    prep_w      <<<dim3(160),   256, 0, stream>>>(W1, W2, W1F, W2F, RBF);
    gemm1_mfma  <<<dim3(1024),  512, 0, stream>>>(X, W1F, b1, reg0);
    fftfilt_mfma<<<dim3(3072),  256, 0, stream>>>(reg0, reg1, RBF);
    gemm2_mfma  <<<dim3(512),   256, 0, stream>>>(reg1, W2F, b2, X, OUT);
}

// Round 20
// 153.119 us; speedup vs baseline: 1.0613x; 1.0613x over previous
//
#include <hip/hip_runtime.h>
#include <math.h>

// ---------------------------------------------------------------------------
// out = x + W2·gelu_fftlow(W1·x + b1) + b2        (r18 best-state, re-anchored)
//  prep_w:       W1,W2 f32 -> bf16 fragment-direct tables + swizzled
//                Dirichlet table RbF.
//  gemm1_mfma:   xs1 = gelu(X·W1^T + b1); BM=128, grid 512 (r18-verified;
//                r19's BM=64 regressed +9us — geometry is a local optimum).
//  fftfilt_mfma: per-plane circular low-pass; Rb from RbF (r18-verified).
//  gemm2_mfma:   nt last-touch streams + XCD swizzle (r15/r17/r18-verified).
// ws: xs1 (25.2MB) | xs2 (25.2MB) | W1F (288KB) | W2F (288KB) | RbF (8KB)
// ---------------------------------------------------------------------------

typedef unsigned short u16;
typedef __attribute__((ext_vector_type(8))) short bf16x8;
typedef __attribute__((ext_vector_type(4))) float f32x4;

__device__ __forceinline__ float bf2f(u16 u) {
    union { unsigned int i; float f; } v; v.i = ((unsigned int)u) << 16; return v.f;
}
__device__ __forceinline__ u16 f2bf(float f) {
    union { unsigned int i; float f; } v; v.f = f;
    unsigned int r = v.i + 0x7FFFu + ((v.i >> 16) & 1u);   // RNE
    return (u16)(r >> 16);
}
__device__ __forceinline__ unsigned cvtpk(float lo, float hi) {
    unsigned r;
    asm("v_cvt_pk_bf16_f32 %0, %1, %2" : "=v"(r) : "v"(lo), "v"(hi));
    return r;
}
// LDS-only barrier (gemm2 steady state; measured neutral vs __syncthreads).
__device__ __forceinline__ void bar_lgkm() {
    asm volatile("s_waitcnt lgkmcnt(0)" ::: "memory");
    __builtin_amdgcn_s_barrier();
    asm volatile("" ::: "memory");
}

// row XOR-swizzle, u16 units; rowU16 multiple of 64 (128B rows)
__device__ __forceinline__ int swz(int row, int rowU16, int colU16) {
    int cb = colU16 & ~7;
    int ci = colU16 & 7;
    return row * rowU16 + (cb ^ ((row & 7) << 3)) + ci;
}
// gemm2 As swizzle
__device__ __forceinline__ int swz2(int row, int colU16) {
    int cb = colU16 >> 3;
    int ci = colU16 & 7;
    cb ^= (row & 7) ^ ((row >> 3) & 7);
    return row * 192 + (cb << 3) + ci;
}
// fftfilt's own swizzle (verified)
__device__ __forceinline__ int swzb(int row, int byteInRow) {
    return (row << 7) + (byteInRow ^ ((row & 7) << 4));
}
__device__ __forceinline__ int swzi(int row, int col) {
    return swzb(row, col << 1) >> 1;
}

#define PI_32 0.09817477042468103f

// ===================== prep_w: weight tables + Dirichlet table =============
__global__ __launch_bounds__(256) void prep_w(
    const float* __restrict__ W1, const float* __restrict__ W2,
    u16* __restrict__ W1F, u16* __restrict__ W2F, u16* __restrict__ RBF)
{
    int tid = blockIdx.x * 256 + threadIdx.x;
    if (tid < 18432) {
        int c = tid;
        int l  = c & 63;
        int kk = (c >> 6) & 1;
        int r  = c >> 7;            // (kt*4+g)*3 + nj
        int nj = r % 3;
        int gkt = r / 3;            // kt*4+g
        int g  = gkt & 3;
        int kt = gkt >> 2;
        int row = g * 48 + nj * 16 + (l & 15);
        int col = kt * 64 + kk * 32 + ((l >> 4) << 3);
        const float* s = &W1[(size_t)row * 768 + col];
        u16* dst = &W1F[(size_t)c * 8];
        #pragma unroll
        for (int j = 0; j < 8; ++j) dst[j] = f2bf(s[j]);
    } else if (tid < 36864) {
        int c = tid - 18432;
        int l  = c & 63;
        int kk = (c >> 6) % 6;
        int r  = (c >> 6) / 6;      // (ct*2+cw)*2 + cj
        int cj = r & 1;
        int cwct = r >> 1;
        int cw = cwct & 1;
        int ct = cwct >> 1;
        int row = ct * 64 + cw * 32 + cj * 16 + (l & 15);
        int col = kk * 32 + ((l >> 4) << 3);
        const float* s = &W2[(size_t)row * 192 + col];
        u16* dst = &W2F[(size_t)c * 8];
        #pragma unroll
        for (int j = 0; j < 8; ++j) dst[j] = f2bf(s[j]);
    } else if (tid < 40960) {
        int c = tid - 36864;        // 0..4095: Rb entry (i,j), swizzled store
        int i = c >> 6, j = c & 63;
        int d = (i - j) & 63;
        float rr = 0.f;
        for (int k = -16; k < 16; ++k) {
            int md = ((k * d) % 64 + 64) % 64;
            rr += cosf((float)md * PI_32);
        }
        RBF[swzi(i, j)] = f2bf(rr * 0.015625f);
    }
}

// ============================ GEMM1 (MFMA) =================================
// grid 512, 512 threads (8 waves: 2m x 4n), BM=128, BN=192, BK=64
// A double-buffered in LDS (one barrier/K-tile); B direct from W1F.
__global__ __launch_bounds__(512) void gemm1_mfma(
    const float* __restrict__ X, const u16* __restrict__ W1F,
    const float* __restrict__ b1, u16* __restrict__ XS1)
{
    __shared__ u16 As[2][128 * 64];
    const int t  = threadIdx.x, wv = t >> 6, l = t & 63;
    const int m0 = blockIdx.x * 128;
    const int bb = m0 >> 12, mp0 = m0 & 4095;
    const int fr  = l & 15;
    const int fko = (l >> 4) << 3;
    const int wm = (wv & 1) * 64, g = wv >> 1, wn = g * 48;
    const int arow = t >> 2, ac4 = (t & 3) << 4;
    const float* aptr = &X[(size_t)(m0 + arow) * 768 + ac4];

    float4 f0 = *(const float4*)(aptr);
    float4 f1 = *(const float4*)(aptr + 4);
    float4 f2 = *(const float4*)(aptr + 8);
    float4 f3 = *(const float4*)(aptr + 12);

    f32x4 acc[4][3];
    #pragma unroll
    for (int i = 0; i < 4; ++i)
        #pragma unroll
        for (int j = 0; j < 3; ++j)
            acc[i][j] = (f32x4){0.f, 0.f, 0.f, 0.f};

    for (int kt = 0; kt < 12; ++kt) {
        u16* Ab = &As[kt & 1][0];
        {
            uint4 q0, q1;
            q0.x = cvtpk(f0.x, f0.y); q0.y = cvtpk(f0.z, f0.w);
            q0.z = cvtpk(f1.x, f1.y); q0.w = cvtpk(f1.z, f1.w);
            q1.x = cvtpk(f2.x, f2.y); q1.y = cvtpk(f2.z, f2.w);
            q1.z = cvtpk(f3.x, f3.y); q1.w = cvtpk(f3.z, f3.w);
            *(uint4*)&Ab[swz(arow, 64, ac4)]     = q0;
            *(uint4*)&Ab[swz(arow, 64, ac4 + 8)] = q1;
        }
        if (kt < 11) {   // prefetch next K-tile while MFMA runs
            const float* np = aptr + (kt + 1) * 64;
            f0 = *(const float4*)(np);
            f1 = *(const float4*)(np + 4);
            f2 = *(const float4*)(np + 8);
            f3 = *(const float4*)(np + 12);
        }
        __syncthreads();
        #pragma unroll
        for (int kk = 0; kk < 2; ++kk) {
            const size_t base = ((size_t)((kt * 4 + g) * 3) * 2 + kk) * 512 + (size_t)l * 8;
            bf16x8 b0  = *(const bf16x8*)&W1F[base];
            bf16x8 b1v = *(const bf16x8*)&W1F[base + 1024];   // nj=1
            bf16x8 b2v = *(const bf16x8*)&W1F[base + 2048];   // nj=2
            #pragma unroll
            for (int mi = 0; mi < 4; ++mi) {
                bf16x8 a = *(bf16x8*)&Ab[swz(wm + mi * 16 + fr, 64, kk * 32 + fko)];
                acc[mi][0] = __builtin_amdgcn_mfma_f32_16x16x32_bf16(a, b0,  acc[mi][0], 0, 0, 0);
                acc[mi][1] = __builtin_amdgcn_mfma_f32_16x16x32_bf16(a, b1v, acc[mi][1], 0, 0, 0);
                acc[mi][2] = __builtin_amdgcn_mfma_f32_16x16x32_bf16(a, b2v, acc[mi][2], 0, 0, 0);
            }
        }
        // no second barrier: double-buffered
    }

    // ---- epilogue: bias + exact gelu -> xs1 [d][m'] ----
    const int mr = mp0 + wm + (l >> 4) * 4;
    #pragma unroll
    for (int nj = 0; nj < 3; ++nj) {
        const int d = wn + nj * 16 + fr;
        const float bias = b1[d];
        u16* dst = XS1 + ((size_t)(bb * 192 + d) << 12);
        #pragma unroll
        for (int mi = 0; mi < 4; ++mi) {
            float v0, v1, v2, v3;
            v0 = acc[mi][nj][0] + bias; v0 = 0.5f*v0*(1.f+erff(v0*0.70710678118f));
            v1 = acc[mi][nj][1] + bias; v1 = 0.5f*v1*(1.f+erff(v1*0.70710678118f));
            v2 = acc[mi][nj][2] + bias; v2 = 0.5f*v2*(1.f+erff(v2*0.70710678118f));
            v3 = acc[mi][nj][3] + bias; v3 = 0.5f*v3*(1.f+erff(v3*0.70710678118f));
            uint2 pk;
            pk.x = cvtpk(v0, v1);
            pk.y = cvtpk(v2, v3);
            *(uint2*)&dst[mr + mi * 16] = pk;
        }
    }
}

// ===================== FFT low-pass: 1 plane / 256-thread block ============
// 4 waves split the 16-tile stages (wave wv owns ti = wv). LDS 24KB.
// Rb table linear-copied from precomputed RbF (L2-hot).
__global__ __launch_bounds__(256) void fftfilt_mfma(
    const u16* __restrict__ XS1, u16* __restrict__ XS2,
    const u16* __restrict__ RBF)
{
    __shared__ u16  Rb[64 * 64];     // 8KB, R table (swizzled, symmetric)
    __shared__ u16  P [64 * 64];     // 8KB, plane; reused for |Y|
    __shared__ u16  Tt[64 * 64];     // 8KB, (P·R)^T

    const int t  = threadIdx.x;
    const int wv = t >> 6;
    const int l  = t & 63;

    const size_t base = (size_t)blockIdx.x << 12;
    const u16* src = XS1 + base;
    u16*       dst = XS2 + base;

    // ---- Rb: linear copy of precomputed swizzled table (2 x 16B/thread) ----
    #pragma unroll
    for (int it = 0; it < 2; ++it) {
        const int e0 = (it * 256 + t) * 8;
        *(bf16x8*)&Rb[e0] = *(const bf16x8*)&RBF[e0];
    }
    // ---- load plane (512 x 16B chunks over 256 threads) ----
    #pragma unroll
    for (int it = 0; it < 2; ++it) {
        const int e0 = (it * 256 + t) * 8;
        bf16x8 v = *(const bf16x8*)&src[e0];
        *(bf16x8*)&P[swzi(e0 >> 6, e0 & 63)] = v;
    }
    __syncthreads();

    // ---- rank-4 correction moments (each wave computes identical p1..p4) --
    float vc = 0.f, vs = 0.f;
    #pragma unroll
    for (int jc = 0; jc < 8; ++jc) {
        bf16x8 v = *(bf16x8*)&P[swzi(l, jc * 8)];
        vc += bf2f((u16)v[0]) - bf2f((u16)v[2]) + bf2f((u16)v[4]) - bf2f((u16)v[6]);
        vs += bf2f((u16)v[1]) - bf2f((u16)v[3]) + bf2f((u16)v[5]) - bf2f((u16)v[7]);
    }
    const float cl = (l & 1) ? 0.f : ((l & 2) ? -1.f : 1.f);
    const float sl = (l & 1) ? ((l & 2) ? -1.f : 1.f) : 0.f;
    float p1 = cl * vc, p2 = cl * vs, p3 = sl * vc, p4 = sl * vs;
    #pragma unroll
    for (int off = 32; off; off >>= 1) {
        p1 += __shfl_xor(p1, off);
        p2 += __shfl_xor(p2, off);
        p3 += __shfl_xor(p3, off);
        p4 += __shfl_xor(p4, off);
    }

    const int fr = l & 15;
    const int fk = (l >> 4) << 4;
    const int ti = wv;                      // wave owns one ti block

    // ---- stage 1: T1 = P·R (tiles ti=wv, tj=0..3), stored transposed ----
    #pragma unroll
    for (int tj = 0; tj < 4; ++tj) {
        f32x4 acc = {0.f, 0.f, 0.f, 0.f};
        #pragma unroll
        for (int kk = 0; kk < 2; ++kk) {
            bf16x8 a = *(bf16x8*)&P [swzb(ti * 16 + fr, (kk << 6) + fk) >> 1];
            bf16x8 b = *(bf16x8*)&Rb[swzb(tj * 16 + fr, (kk << 6) + fk) >> 1];
            acc = __builtin_amdgcn_mfma_f32_16x16x32_bf16(a, b, acc, 0, 0, 0);
        }
        const int n2 = tj * 16 + fr;
        const int w0 = ti * 16 + ((l >> 4) << 2);
        uint2 pk;
        pk.x = cvtpk(acc[0], acc[1]);
        pk.y = cvtpk(acc[2], acc[3]);
        *(uint2*)&Tt[swzb(n2, w0 << 1) >> 1] = pk;
    }
    __syncthreads();

    // ---- stage 2: Y = R·T1 + corr; |Y| -> P (rows ti*16..) ----
    const float inv4096 = 1.f / 4096.f;
    #pragma unroll
    for (int tj = 0; tj < 4; ++tj) {
        f32x4 acc = {0.f, 0.f, 0.f, 0.f};
        #pragma unroll
        for (int kk = 0; kk < 2; ++kk) {
            bf16x8 a = *(bf16x8*)&Rb[swzb(ti * 16 + fr, (kk << 6) + fk) >> 1];
            bf16x8 b = *(bf16x8*)&Tt[swzb(tj * 16 + fr, (kk << 6) + fk) >> 1];
            acc = __builtin_amdgcn_mfma_f32_16x16x32_bf16(a, b, acc, 0, 0, 0);
        }
        const int a0   = ti * 16 + ((l >> 4) << 2);
        const int bcol = tj * 16 + fr;
        const float cb = (bcol & 1) ? 0.f : ((bcol & 2) ? -1.f : 1.f);
        const float sb = (bcol & 1) ? ((bcol & 2) ? -1.f : 1.f) : 0.f;
        #pragma unroll
        for (int r = 0; r < 4; ++r) {
            const int aa = a0 + r;
            const float ca = (aa & 1) ? 0.f : ((aa & 2) ? -1.f : 1.f);
            const float sa = (aa & 1) ? ((aa & 2) ? -1.f : 1.f) : 0.f;
            const float corr = inv4096 *
                (p2 * sa * cb - p1 * sa * sb - p4 * ca * cb + p3 * ca * sb);
            P[swzi(aa, bcol)] = f2bf(fabsf(acc[r] + corr));
        }
    }
    __syncthreads();

    // ---- coalesced copy-out ----
    #pragma unroll
    for (int it = 0; it < 2; ++it) {
        const int e0 = (it * 256 + t) * 8;
        bf16x8 v = *(bf16x8*)&P[swzi(e0 >> 6, e0 & 63)];
        *(bf16x8*)&dst[e0] = v;
    }
}

// ============================ GEMM2 (MFMA) =================================
// r15/r17/r18-VERIFIED: grid 512, 256 threads (4 waves: 2m x 2c), BM=128;
// nontemporal xs2/X loads and OUT stores (all last-touch); XCD swizzle.
__global__ __launch_bounds__(256, 2) void gemm2_mfma(
    const u16* __restrict__ XS2, const u16* __restrict__ W2F,
    const float* __restrict__ b2, const float* __restrict__ X,
    float* __restrict__ OUT)
{
    __shared__ float Ot[2][128 * 68];     // 69632 B; As overlays (dead after areg)
    u16* As = (u16*)&Ot[0][0];            // [m][d] swz2, 128*192 u16 = 48KB
    const int t  = threadIdx.x, wv = t >> 6, l = t & 63;
    const int bid = ((blockIdx.x & 7) << 6) | (blockIdx.x >> 3);   // XCD swizzle
    const int m0 = bid * 128;
    const int b  = m0 >> 12, mp0 = m0 & 4095;
    const int fr  = l & 15;
    const int fko = (l >> 4) << 3;
    const int wm = (wv & 1) * 64, cw = wv >> 1, wc = cw * 32;

    // ---- fused transpose staging: read [d][m'] coalesced (nt), scatter ----
    #pragma unroll
    for (int i = 0; i < 12; ++i) {
        const int e = t + i * 256;        // 0..3071
        const int d = e >> 4, mc = e & 15;
        bf16x8 v = __builtin_nontemporal_load(
            (const bf16x8*)&XS2[((size_t)(b * 192 + d) << 12) + mp0 + mc * 8]);
        #pragma unroll
        for (int j = 0; j < 8; ++j)
            As[swz2(mc * 8 + j, d)] = (u16)v[j];
    }
    __syncthreads();

    // ---- A fragments to registers ----
    bf16x8 areg[4][6];
    #pragma unroll
    for (int mi = 0; mi < 4; ++mi)
        #pragma unroll
        for (int kk = 0; kk < 6; ++kk)
            areg[mi][kk] = *(bf16x8*)&As[swz2(wm + mi * 16 + fr, kk * 32 + fko)];
    __syncthreads();                      // As now dead; Ot safe to write

    // epilogue read mapping (fixed per thread)
    const int erow = t >> 4;              // + p*16
    const int ec4  = (t & 15) << 2;       // f32 col

    // ---- prefetch X for tile ct=0 (nontemporal: streamed once) ----
    f32x4 xreg[8];
    #pragma unroll
    for (int p = 0; p < 8; ++p)
        xreg[p] = __builtin_nontemporal_load(
            (const f32x4*)&X[(size_t)(m0 + erow + p * 16) * 768 + ec4]);

    // ---- 12 c-tiles, B direct from W2F (L2-hot, cached) ----
    for (int ct = 0; ct < 12; ++ct) {
        f32x4 acc[4][2];   // [mi][cj]; c = lane&15, m = (l>>4)*4 + reg
        #pragma unroll
        for (int i = 0; i < 4; ++i) {
            acc[i][0] = (f32x4){0.f, 0.f, 0.f, 0.f};
            acc[i][1] = (f32x4){0.f, 0.f, 0.f, 0.f};
        }
        #pragma unroll
        for (int kk = 0; kk < 6; ++kk) {
            const size_t base = (((size_t)(ct * 2 + cw) * 2) * 6 + kk) * 512 + (size_t)l * 8;
            bf16x8 bv0 = *(const bf16x8*)&W2F[base];
            bf16x8 bv1 = *(const bf16x8*)&W2F[base + 3072];   // cj=1
            #pragma unroll
            for (int mi = 0; mi < 4; ++mi) {
                acc[mi][0] = __builtin_amdgcn_mfma_f32_16x16x32_bf16(areg[mi][kk], bv0, acc[mi][0], 0, 0, 0);
                acc[mi][1] = __builtin_amdgcn_mfma_f32_16x16x32_bf16(areg[mi][kk], bv1, acc[mi][1], 0, 0, 0);
            }
        }
        // ---- stage acc into f32 LDS tile (dbuf) ----
        float* Ob = &Ot[ct & 1][0];
        #pragma unroll
        for (int cj = 0; cj < 2; ++cj) {
            const int cc = wc + cj * 16 + fr;
            #pragma unroll
            for (int mi = 0; mi < 4; ++mi) {
                const int mrow = wm + mi * 16 + (l >> 4) * 4;
                Ob[(mrow + 0) * 68 + cc] = acc[mi][cj][0];
                Ob[(mrow + 1) * 68 + cc] = acc[mi][cj][1];
                Ob[(mrow + 2) * 68 + cc] = acc[mi][cj][2];
                Ob[(mrow + 3) * 68 + cc] = acc[mi][cj][3];
            }
        }
        // ---- issue next tile's X loads BEFORE the barrier (nt) ----
        f32x4 xnext[8];
        if (ct < 11) {
            #pragma unroll
            for (int p = 0; p < 8; ++p)
                xnext[p] = __builtin_nontemporal_load(
                    (const f32x4*)&X[(size_t)(m0 + erow + p * 16) * 768
                                     + (ct + 1) * 64 + ec4]);
        }
        bar_lgkm();     // LDS-only drain; stores/loads stay in flight
        // ---- coalesced RMW: 256B bursts along c, nontemporal stores ----
        const int c0 = ct * 64;
        const float4 bv4 = *(const float4*)&b2[c0 + ec4];
        #pragma unroll
        for (int p = 0; p < 8; ++p) {
            const int row = erow + p * 16;
            const float* s = &Ob[row * 68 + ec4];
            const size_t off = (size_t)(m0 + row) * 768 + c0 + ec4;
            f32x4 o;
            o[0] = (s[0] + bv4.x) + xreg[p][0];
            o[1] = (s[1] + bv4.y) + xreg[p][1];
            o[2] = (s[2] + bv4.z) + xreg[p][2];
            o[3] = (s[3] + bv4.w) + xreg[p][3];
            __builtin_nontemporal_store(o, (f32x4*)&OUT[off]);
        }
        if (ct < 11) {
            #pragma unroll
            for (int p = 0; p < 8; ++p) xreg[p] = xnext[p];
        }
        // next iteration writes the other Ot buffer; reads of this one are
        // protected by the barrier inside the next iteration.
    }
}

// ---------------------------------------------------------------------------
extern "C" void kernel_launch(void* const* d_in, const int* in_sizes, int n_in,
                              void* d_out, int out_size, void* d_ws, size_t ws_size,
                              hipStream_t stream) {
    (void)in_sizes; (void)n_in; (void)out_size; (void)ws_size;
    const float* X  = (const float*)d_in[0];
    const float* W1 = (const float*)d_in[1];
    const float* b1 = (const float*)d_in[2];
    const float* W2 = (const float*)d_in[3];
    const float* b2 = (const float*)d_in[4];
    float* OUT = (float*)d_out;

    u16* reg0 = (u16*)d_ws;                              // xs1
    u16* reg1 = reg0 + (size_t)16 * 192 * 4096;          // xs2
    u16* W1F  = reg1 + (size_t)16 * 192 * 4096;          // 147456 u16
    u16* W2F  = W1F + 147456;                            // 147456 u16
    u16* RBF  = W2F + 147456;                            // 4096 u16

    prep_w      <<<dim3(160),   256, 0, stream>>>(W1, W2, W1F, W2F, RBF);
    gemm1_mfma  <<<dim3(512),   512, 0, stream>>>(X, W1F, b1, reg0);
    fftfilt_mfma<<<dim3(3072),  256, 0, stream>>>(reg0, reg1, RBF);
    gemm2_mfma  <<<dim3(512),   256, 0, stream>>>(reg1, W2F, b2, X, OUT);
}